// Round 7
// baseline (1726.531 us; speedup 1.0000x reference)
//
#include <hip/hip_runtime.h>

#define B_    2
#define N_    4096
#define E_    262144
#define F_    5
#define ED    150
#define ND    100
#define NIN   154
#define EIN   9
#define GN    32      // nodes per block; grid = 2*4096/32 = 256 = 1 block/CU
#define HSTR  168     // ushort stride for h rows (336B = 21 superbanks, odd -> spread)
#define NSTR  164     // f32 stride for nin
#define ASTR  116     // f32 stride for hA/hB
#define CSTR  104

typedef __attribute__((ext_vector_type(8)))  short bf16x8;
typedef __attribute__((ext_vector_type(16))) float f32x16;
typedef __attribute__((ext_vector_type(4)))  float f4;

static __device__ __forceinline__ unsigned short f2bf(float x) {
    unsigned int u = __float_as_uint(x);
    return (unsigned short)((u + 0x7fffu + ((u >> 16) & 1u)) >> 16);
}
static __device__ __forceinline__ float bf2f(unsigned short s) {
    return __uint_as_float(((unsigned int)s) << 16);
}

struct __align__(16) SMem {
    unsigned short h_hi[2][64][HSTR];   // 43008 B  layer-1 out, split-hi, dbuf
    unsigned short h_lo[2][64][HSTR];   // 43008 B
    float nin[GN][NSTR];                // 20992 B
    float hA[GN][ASTR];                 // 14848 B
    float hB[GN][ASTR];                 // 14848 B
    float hC[GN][CSTR];                 // 13312 B   -> 150016 B total (1 block/CU)
};

// one tail MLP layer for 32 nodes: Y = relu(X @ Wg + bias), via 32x32x16 split-bf16 MFMA
template<int KS, int KR, int XS, int YS>
static __device__ __forceinline__ void tail_layer(const float* __restrict__ X,
                                                  float* __restrict__ Y,
                                                  const float* __restrict__ Wg,
                                                  const float* __restrict__ bias,
                                                  int wave, int lane)
{
    if (wave >= 4) return;
    const int jc  = wave * 32 + (lane & 31);
    const int hi  = lane >> 5;
    const int row = lane & 31;
    f32x16 C;
    #pragma unroll
    for (int r = 0; r < 16; ++r) C[r] = 0.0f;
    #pragma unroll
    for (int s = 0; s < KS; ++s) {
        bf16x8 ah, al, bhv, blv;
        f4 xa = *(const f4*)&X[row * XS + s * 16 + 4 * hi];
        f4 xb = *(const f4*)&X[row * XS + s * 16 + 8 + 4 * hi];
        #pragma unroll
        for (int e = 0; e < 8; ++e) {
            float x = (e < 4) ? xa[e] : xb[e - 4];
            unsigned short h = f2bf(x);
            ah[e] = (short)h;  al[e] = (short)f2bf(x - bf2f(h));
            int k = s * 16 + (e & 3) + 8 * (e >> 2) + 4 * hi;
            float w = (k < KR && jc < ND) ? Wg[k * ND + jc] : 0.0f;
            unsigned short wh = f2bf(w);
            bhv[e] = (short)wh;  blv[e] = (short)f2bf(w - bf2f(wh));
        }
        C = __builtin_amdgcn_mfma_f32_32x32x16_bf16(ah, bhv, C, 0, 0, 0);
        C = __builtin_amdgcn_mfma_f32_32x32x16_bf16(ah, blv, C, 0, 0, 0);
        C = __builtin_amdgcn_mfma_f32_32x32x16_bf16(al, bhv, C, 0, 0, 0);
    }
    if (jc < ND) {
        float bv = bias[jc];
        #pragma unroll
        for (int r = 0; r < 16; ++r) {
            int node = (r & 3) + 8 * (r >> 2) + 4 * hi;
            Y[node * YS + jc] = fmaxf(C[r] + bv, 0.0f);
        }
    }
}

__global__ __launch_bounds__(512, 1)
void deltagn_v7(const float* __restrict__ V,  const float* __restrict__ dt,
                const float* __restrict__ eW1, const float* __restrict__ eb1,
                const float* __restrict__ eW2, const float* __restrict__ eb2,
                const float* __restrict__ nW1, const float* __restrict__ nb1,
                const float* __restrict__ nW2, const float* __restrict__ nb2,
                const float* __restrict__ nW3, const float* __restrict__ nb3,
                const float* __restrict__ lW,  const float* __restrict__ lb,
                const int* __restrict__ Rs,   const int* __restrict__ Rr,
                float* __restrict__ out)
{
    __shared__ SMem sm;
    const int t    = threadIdx.x;
    const int wave = t >> 6;
    const int lane = t & 63;
    const int blk  = blockIdx.x;
    const int b    = blk >> 7;            // 128 blocks per batch
    const int n0   = (blk & 127) * GN;
    const float HALF = 3.0f, BOXF = 6.0f;
    const float dtv = dt[b];

    // ---- zero nin (incl. pads) and hA/hB k-pads ----
    {
        float* nf = &sm.nin[0][0];
        for (int i = t; i < GN * NSTR; i += 512) nf[i] = 0.0f;
        for (int i = t; i < GN * 16; i += 512) {
            sm.hA[i >> 4][100 + (i & 15)] = 0.0f;
            sm.hB[i >> 4][100 + (i & 15)] = 0.0f;
        }
    }

    // ---- consumer waves 0-4: W2 B-fragments global -> registers, split bf16 hi/lo ----
    // Live set during loop: bh(40)+bl(40)+C0/C1(32)+misc ~ 120 <= 128-VGPR budget (no spill).
    bf16x8 bh[10], bl[10];
    float  b2v = 0.0f;
    if (wave < 5) {
        const int col = wave * 32 + (lane & 31);
        const int hi  = lane >> 5;
        #pragma unroll
        for (int s = 0; s < 10; ++s) {
            #pragma unroll
            for (int e = 0; e < 8; ++e) {
                int k = s * 16 + (e & 3) + 8 * (e >> 2) + 4 * hi;
                float w = (k < ED && col < ED) ? eW2[k * ED + col] : 0.0f;
                unsigned short h = f2bf(w);
                bh[s][e] = (short)h;  bl[s][e] = (short)f2bf(w - bf2f(h));
            }
        }
        b2v = (col < ED) ? eb2[col] : 0.0f;
    }

    // int64-vs-int32 index detection (values < 4096 => odd int32 words all zero iff int64)
    // Only producer waves use the result.
    const bool i64S = (__ballot(Rs[2 * lane + 1] == 0) == ~0ull);
    const bool i64R = (__ballot(Rr[2 * lane + 1] == 0) == ~0ull);

    __syncthreads();   // nin zeros visible before loop writes

    // phase-B: one 16-col kstep of h = relu(Ein @ eW1 + eb1), split+pack to LDS
    auto phaseB = [&](const float (&ein)[EIN], int ks, int buf) {
        const int sb = ks * 16;
        float hv[16];
        int cidx[16];
        #pragma unroll
        for (int r = 0; r < 16; ++r) {
            int c = sb + r;
            cidx[r] = (c < ED) ? c : (ED - 1);
            hv[r] = (c < ED) ? eb1[c] : 0.0f;
        }
        #pragma unroll
        for (int q = 0; q < EIN; ++q) {
            const float* wr = eW1 + q * ED;
            #pragma unroll
            for (int r = 0; r < 16; ++r) hv[r] += ein[q] * wr[cidx[r]];   // scalar-broadcast
        }
        #pragma unroll
        for (int r = 0; r < 16; ++r)
            hv[r] = (sb + r < ED) ? fmaxf(hv[r], 0.0f) : 0.0f;
        constexpr int rm0[8] = {0,1,2,3,8,9,10,11};
        constexpr int rm1[8] = {4,5,6,7,12,13,14,15};
        bf16x8 h0, h1, l0, l1;
        #pragma unroll
        for (int e = 0; e < 8; ++e) {
            float x0 = hv[rm0[e]], x1 = hv[rm1[e]];
            unsigned short a0 = f2bf(x0), a1 = f2bf(x1);
            h0[e] = (short)a0;  l0[e] = (short)f2bf(x0 - bf2f(a0));
            h1[e] = (short)a1;  l1[e] = (short)f2bf(x1 - bf2f(a1));
        }
        *(bf16x8*)&sm.h_hi[buf][lane][sb + 0] = h0;
        *(bf16x8*)&sm.h_hi[buf][lane][sb + 8] = h1;
        *(bf16x8*)&sm.h_lo[buf][lane][sb + 0] = l0;
        *(bf16x8*)&sm.h_lo[buf][lane][sb + 8] = l1;
    };

    // ======== main loop: producer waves 5-7 fill h[g&1]; consumer waves 0-4 MFMA h[(g-1)&1] ========
    for (int g = 0; g <= GN; ++g) {
        if (wave >= 5 && g < GN) {   // -------- producers --------
            float ein[EIN];
            const int eb = b * E_ + (n0 + g) * 64 + lane;
            const int si = i64S ? Rs[2 * eb] : Rs[eb];
            const int ri = i64R ? Rr[2 * eb] : Rr[eb];
            const float* vs = V + (b * N_ + si) * F_;
            const float* vr = V + (b * N_ + ri) * F_;
            float d0 = vs[1] - vr[1], d1 = vs[2] - vr[2];
            d0 = (d0 >  HALF) ? d0 - BOXF : d0;
            d0 = (d0 <= -HALF) ? d0 + BOXF : d0;
            d1 = (d1 >  HALF) ? d1 - BOXF : d1;
            d1 = (d1 <= -HALF) ? d1 + BOXF : d1;
            ein[0] = vs[0]; ein[1] = vs[3]; ein[2] = vs[4];
            ein[3] = vr[0]; ein[4] = vr[3]; ein[5] = vr[4];
            ein[6] = d0;    ein[7] = d1;    ein[8] = dtv;

            const int p   = wave - 5;      // 0,1,2
            const int buf = g & 1;
            phaseB(ein, p,     buf);
            phaseB(ein, p + 3, buf);
            phaseB(ein, p + 6, buf);
            if (p == 0) phaseB(ein, 9, buf);
            if (wave == 7 && lane < 4) {   // nin extras for node g
                const int bn5 = (b * N_ + n0 + g) * F_;
                if (lane == 0) sm.nin[g][0]       = V[bn5 + 0];
                if (lane == 1) sm.nin[g][1]       = V[bn5 + 3];
                if (lane == 2) sm.nin[g][2]       = V[bn5 + 4];
                if (lane == 3) sm.nin[g][NIN - 1] = dtv;
            }
        }

        if (wave < 5 && g >= 1) {   // -------- consumers: edge GEMM for node g-1 --------
            const int buf  = (g - 1) & 1;
            const int row  = lane & 31;
            const int eoff = (lane >> 5) * 8;
            f32x16 C0, C1;
            #pragma unroll
            for (int r = 0; r < 16; ++r) { C0[r] = 0.0f; C1[r] = 0.0f; }
            #pragma unroll
            for (int s = 0; s < 10; ++s) {
                const int cb = s * 16 + eoff;
                bf16x8 ah0 = *(const bf16x8*)&sm.h_hi[buf][row     ][cb];
                bf16x8 al0 = *(const bf16x8*)&sm.h_lo[buf][row     ][cb];
                bf16x8 ah1 = *(const bf16x8*)&sm.h_hi[buf][row + 32][cb];
                bf16x8 al1 = *(const bf16x8*)&sm.h_lo[buf][row + 32][cb];
                C0 = __builtin_amdgcn_mfma_f32_32x32x16_bf16(ah0, bh[s], C0, 0, 0, 0);
                C1 = __builtin_amdgcn_mfma_f32_32x32x16_bf16(ah1, bh[s], C1, 0, 0, 0);
                C0 = __builtin_amdgcn_mfma_f32_32x32x16_bf16(ah0, bl[s], C0, 0, 0, 0);
                C1 = __builtin_amdgcn_mfma_f32_32x32x16_bf16(ah1, bl[s], C1, 0, 0, 0);
                C0 = __builtin_amdgcn_mfma_f32_32x32x16_bf16(al0, bh[s], C0, 0, 0, 0);
                C1 = __builtin_amdgcn_mfma_f32_32x32x16_bf16(al1, bh[s], C1, 0, 0, 0);
            }
            float colsum = 0.0f;
            #pragma unroll
            for (int r = 0; r < 16; ++r)
                colsum += fmaxf(C0[r] + b2v, 0.0f) + fmaxf(C1[r] + b2v, 0.0f);
            colsum += __shfl_xor(colsum, 32);
            const int col = wave * 32 + lane;
            if (lane < 32 && col < ED) sm.nin[g - 1][3 + col] = colsum;
        }
        __syncthreads();
    }

    // ======== tail: batched node-MLP for all 32 nodes (split-bf16 MFMA) ========
    tail_layer<10, NIN, NSTR, ASTR>(&sm.nin[0][0], &sm.hA[0][0], nW1, nb1, wave, lane);
    __syncthreads();
    tail_layer<7, ND, ASTR, ASTR>(&sm.hA[0][0], &sm.hB[0][0], nW2, nb2, wave, lane);
    __syncthreads();
    tail_layer<7, ND, ASTR, CSTR>(&sm.hB[0][0], &sm.hC[0][0], nW3, nb3, wave, lane);
    __syncthreads();

    // ---- head: 32 nodes x 4 outputs on threads 0..127 ----
    if (t < GN * 4) {
        const int node = t >> 2, o = t & 3;
        float a = lb[o];
        #pragma unroll 10
        for (int k = 0; k < ND; ++k) a += sm.hC[node][k] * lW[k * 4 + o];
        const int bn = b * N_ + n0 + node;
        float nv = V[bn * F_ + 1 + o] + a;
        if (o < 2) {
            nv = (nv >=  HALF) ? nv - BOXF : nv;
            nv = (nv <  -HALF) ? nv + BOXF : nv;
        }
        out[bn * 4 + o] = nv;
    }
}

extern "C" void kernel_launch(void* const* d_in, const int* in_sizes, int n_in,
                              void* d_out, int out_size, void* d_ws, size_t ws_size,
                              hipStream_t stream) {
    (void)in_sizes; (void)n_in; (void)d_ws; (void)ws_size; (void)out_size;
    const float* V   = (const float*)d_in[0];
    const float* dt  = (const float*)d_in[1];
    const float* eW1 = (const float*)d_in[2];
    const float* eb1 = (const float*)d_in[3];
    const float* eW2 = (const float*)d_in[4];
    const float* eb2 = (const float*)d_in[5];
    const float* nW1 = (const float*)d_in[6];
    const float* nb1 = (const float*)d_in[7];
    const float* nW2 = (const float*)d_in[8];
    const float* nb2 = (const float*)d_in[9];
    const float* nW3 = (const float*)d_in[10];
    const float* nb3 = (const float*)d_in[11];
    const float* lW  = (const float*)d_in[12];
    const float* lb  = (const float*)d_in[13];
    const int* Rs = (const int*)d_in[14];
    const int* Rr = (const int*)d_in[15];
    float* out = (float*)d_out;

    deltagn_v7<<<dim3(256), dim3(512), 0, stream>>>(
        V, dt, eW1, eb1, eW2, eb2, nW1, nb1, nW2, nb2, nW3, nb3, lW, lb, Rs, Rr, out);
}

// Round 8
// 1657.179 us; speedup vs baseline: 1.0418x; 1.0418x over previous
//
#include <hip/hip_runtime.h>

#define B_    2
#define N_    4096
#define E_    262144
#define F_    5
#define ED    150
#define ND    100
#define NIN   154
#define EIN   9
#define GN    32      // nodes per block; grid = 2*4096/32 = 256 = 1 block/CU
#define HSTR  168     // ushort stride (336B rows): 16B-aligned; b128 col-reads hit the 4-clk floor
#define NSTR  164     // f32 stride for nin
#define ASTR  116     // f32 stride for hA/hB
#define CSTR  104

typedef __attribute__((ext_vector_type(8)))  short bf16x8;
typedef __attribute__((ext_vector_type(16))) float f32x16;
typedef __attribute__((ext_vector_type(4)))  float f4;

static __device__ __forceinline__ unsigned short f2bf(float x) {
    unsigned int u = __float_as_uint(x);
    return (unsigned short)((u + 0x7fffu + ((u >> 16) & 1u)) >> 16);
}
static __device__ __forceinline__ float bf2f(unsigned short s) {
    return __uint_as_float(((unsigned int)s) << 16);
}
// swap bits 2<->3 of k so a lane's 8 frag elems are contiguous (one b128)
static __device__ __forceinline__ int kperm(int k) {
    return (k & ~12) | ((k & 4) << 1) | ((k & 8) >> 1);
}

struct __align__(16) SMem {
    union {
        struct {
            unsigned short h_hi[2][64][HSTR];   // 43008 B  layer-1 out split-hi, dbuf
            unsigned short h_lo[2][64][HSTR];   // 43008 B
        } lp;                                    // 86016 B (main loop)
        struct {
            float hA[GN][ASTR];                 // 14848 B
            float hB[GN][ASTR];                 // 14848 B
            float hC[GN][CSTR];                 // 13312 B
        } tl;                                    // 43008 B (tail, aliases loop region)
    } u;
    unsigned short w_lo[160][HSTR];             // 53760 B  W2^T split-LO (constant, single copy)
    float nin[GN][NSTR];                        // 20992 B  persists loop -> tail
};                                               // 160768 B total <= 163840

// one tail MLP layer for 32 nodes: Y = relu(X @ Wg + bias), via 32x32x16 split-bf16 MFMA
template<int KS, int KR, int XS, int YS>
static __device__ __forceinline__ void tail_layer(const float* __restrict__ X,
                                                  float* __restrict__ Y,
                                                  const float* __restrict__ Wg,
                                                  const float* __restrict__ bias,
                                                  int wave, int lane)
{
    if (wave >= 4) return;
    const int jc  = wave * 32 + (lane & 31);
    const int hi  = lane >> 5;
    const int row = lane & 31;
    f32x16 C;
    #pragma unroll
    for (int r = 0; r < 16; ++r) C[r] = 0.0f;
    #pragma unroll
    for (int s = 0; s < KS; ++s) {
        bf16x8 ah, al, bhv, blv;
        f4 xa = *(const f4*)&X[row * XS + s * 16 + 4 * hi];
        f4 xb = *(const f4*)&X[row * XS + s * 16 + 8 + 4 * hi];
        #pragma unroll
        for (int e = 0; e < 8; ++e) {
            float x = (e < 4) ? xa[e] : xb[e - 4];
            unsigned short h = f2bf(x);
            ah[e] = (short)h;  al[e] = (short)f2bf(x - bf2f(h));
            int k = s * 16 + (e & 3) + 8 * (e >> 2) + 4 * hi;
            float w = (k < KR && jc < ND) ? Wg[k * ND + jc] : 0.0f;
            unsigned short wh = f2bf(w);
            bhv[e] = (short)wh;  blv[e] = (short)f2bf(w - bf2f(wh));
        }
        C = __builtin_amdgcn_mfma_f32_32x32x16_bf16(ah, bhv, C, 0, 0, 0);
        C = __builtin_amdgcn_mfma_f32_32x32x16_bf16(ah, blv, C, 0, 0, 0);
        C = __builtin_amdgcn_mfma_f32_32x32x16_bf16(al, bhv, C, 0, 0, 0);
    }
    if (jc < ND) {
        float bv = bias[jc];
        #pragma unroll
        for (int r = 0; r < 16; ++r) {
            int node = (r & 3) + 8 * (r >> 2) + 4 * hi;
            Y[node * YS + jc] = fmaxf(C[r] + bv, 0.0f);
        }
    }
}

__global__ __launch_bounds__(512, 1)
void deltagn_v8(const float* __restrict__ V,  const float* __restrict__ dt,
                const float* __restrict__ eW1, const float* __restrict__ eb1,
                const float* __restrict__ eW2, const float* __restrict__ eb2,
                const float* __restrict__ nW1, const float* __restrict__ nb1,
                const float* __restrict__ nW2, const float* __restrict__ nb2,
                const float* __restrict__ nW3, const float* __restrict__ nb3,
                const float* __restrict__ lW,  const float* __restrict__ lb,
                const int* __restrict__ Rs,   const int* __restrict__ Rr,
                float* __restrict__ out)
{
    __shared__ SMem sm;
    const int t    = threadIdx.x;
    const int wave = t >> 6;
    const int lane = t & 63;
    const int blk  = blockIdx.x;
    const int b    = blk >> 7;            // 128 blocks per batch
    const int n0   = (blk & 127) * GN;
    const float HALF = 3.0f, BOXF = 6.0f;
    const float dtv = dt[b];

    // int64-vs-int32 index detection (values < 4096 => odd int32 words all zero iff int64)
    const bool i64S = (__ballot(Rs[2 * lane + 1] == 0) == ~0ull);
    const bool i64R = (__ballot(Rr[2 * lane + 1] == 0) == ~0ull);

    // ---- zero nin (incl. pads) and w_lo ----
    {
        float* nf = &sm.nin[0][0];
        for (int i = t; i < GN * NSTR; i += 512) nf[i] = 0.0f;
        int4 z = {0, 0, 0, 0};
        int4* pz = (int4*)&sm.w_lo[0][0];
        for (int i = t; i < (160 * HSTR * 2) / 16; i += 512) pz[i] = z;
    }

    // ---- W2 split: HI part -> registers (waves 0-4, 40 VGPRs) ----
    bf16x8 bh[10];
    float  b2v = 0.0f;
    if (wave < 5) {
        const int col = wave * 32 + (lane & 31);
        const int hi  = lane >> 5;
        #pragma unroll
        for (int s = 0; s < 10; ++s) {
            #pragma unroll
            for (int e = 0; e < 8; ++e) {
                int k = s * 16 + (e & 3) + 8 * (e >> 2) + 4 * hi;
                float w = (k < ED && col < ED) ? eW2[k * ED + col] : 0.0f;
                bh[s][e] = (short)f2bf(w);
            }
        }
        b2v = (col < ED) ? eb2[col] : 0.0f;
    }
    __syncthreads();   // zeros visible

    // ---- W2 split: LO part -> LDS (all waves), kperm'd layout [col][k'] ----
    for (int i = t; i < ED * ED; i += 512) {
        int k = i / ED, n = i - k * ED;            // eW2 is [k][n]
        float w = eW2[i];
        unsigned short hi = f2bf(w);
        sm.w_lo[n][kperm(k)] = f2bf(w - bf2f(hi));
    }
    __syncthreads();

    // phase-B: one 16-col kstep of h = relu(Ein @ eW1 + eb1), split+pack to LDS
    auto phaseB = [&](const float (&ein)[EIN], int ks, int buf) {
        const int sb = ks * 16;
        float hv[16];
        #pragma unroll
        for (int r = 0; r < 16; ++r) {
            const int c  = sb + r;
            const int cs = (c < ED) ? c : 0;       // safe uniform index
            float a = eb1[cs];
            #pragma unroll
            for (int q = 0; q < EIN; ++q) a += ein[q] * eW1[q * ED + cs];
            hv[r] = (c < ED) ? fmaxf(a, 0.0f) : 0.0f;
        }
        constexpr int rm0[8] = {0,1,2,3,8,9,10,11};
        constexpr int rm1[8] = {4,5,6,7,12,13,14,15};
        bf16x8 h0, h1, l0, l1;
        #pragma unroll
        for (int e = 0; e < 8; ++e) {
            float x0 = hv[rm0[e]], x1 = hv[rm1[e]];
            unsigned short a0 = f2bf(x0), a1 = f2bf(x1);
            h0[e] = (short)a0;  l0[e] = (short)f2bf(x0 - bf2f(a0));
            h1[e] = (short)a1;  l1[e] = (short)f2bf(x1 - bf2f(a1));
        }
        *(bf16x8*)&sm.u.lp.h_hi[buf][lane][sb + 0] = h0;
        *(bf16x8*)&sm.u.lp.h_hi[buf][lane][sb + 8] = h1;
        *(bf16x8*)&sm.u.lp.h_lo[buf][lane][sb + 0] = l0;
        *(bf16x8*)&sm.u.lp.h_lo[buf][lane][sb + 8] = l1;
    };

    // ======== main loop: producers (waves 5-7) fill h[g&1]; consumers (0-4) MFMA h[(g-1)&1] ========
    for (int g = 0; g <= GN; ++g) {
        if (wave >= 5 && g < GN) {   // -------- producers --------
            float ein[EIN];
            const int eb = b * E_ + (n0 + g) * 64 + lane;
            const int si = i64S ? Rs[2 * eb] : Rs[eb];
            const int ri = i64R ? Rr[2 * eb] : Rr[eb];
            const float* vs = V + (b * N_ + si) * F_;
            const float* vr = V + (b * N_ + ri) * F_;
            float d0 = vs[1] - vr[1], d1 = vs[2] - vr[2];
            d0 = (d0 >  HALF) ? d0 - BOXF : d0;
            d0 = (d0 <= -HALF) ? d0 + BOXF : d0;
            d1 = (d1 >  HALF) ? d1 - BOXF : d1;
            d1 = (d1 <= -HALF) ? d1 + BOXF : d1;
            ein[0] = vs[0]; ein[1] = vs[3]; ein[2] = vs[4];
            ein[3] = vr[0]; ein[4] = vr[3]; ein[5] = vr[4];
            ein[6] = d0;    ein[7] = d1;    ein[8] = dtv;

            const int p   = wave - 5;      // 0,1,2
            const int buf = g & 1;
            phaseB(ein, p,     buf);
            phaseB(ein, p + 3, buf);
            phaseB(ein, p + 6, buf);
            if (p == 0) phaseB(ein, 9, buf);
            if (wave == 7 && lane < 4) {   // nin extras for node g
                const int bn5 = (b * N_ + n0 + g) * F_;
                if (lane == 0) sm.nin[g][0]       = V[bn5 + 0];
                if (lane == 1) sm.nin[g][1]       = V[bn5 + 3];
                if (lane == 2) sm.nin[g][2]       = V[bn5 + 4];
                if (lane == 3) sm.nin[g][NIN - 1] = dtv;
            }
        }

        if (wave < 5 && g >= 1) {   // -------- consumers: edge GEMM for node g-1 --------
            const int buf  = (g - 1) & 1;
            const int row  = lane & 31;
            const int col  = wave * 32 + (lane & 31);
            const int eoff = (lane >> 5) * 8;
            f32x16 C0, C1;
            #pragma unroll
            for (int r = 0; r < 16; ++r) { C0[r] = 0.0f; C1[r] = 0.0f; }
            #pragma unroll
            for (int s = 0; s < 10; ++s) {
                const int cb = s * 16 + eoff;
                bf16x8 blv = *(const bf16x8*)&sm.w_lo[col][cb];          // B-lo from LDS
                bf16x8 ah0 = *(const bf16x8*)&sm.u.lp.h_hi[buf][row     ][cb];
                bf16x8 al0 = *(const bf16x8*)&sm.u.lp.h_lo[buf][row     ][cb];
                bf16x8 ah1 = *(const bf16x8*)&sm.u.lp.h_hi[buf][row + 32][cb];
                bf16x8 al1 = *(const bf16x8*)&sm.u.lp.h_lo[buf][row + 32][cb];
                C0 = __builtin_amdgcn_mfma_f32_32x32x16_bf16(ah0, bh[s], C0, 0, 0, 0);
                C1 = __builtin_amdgcn_mfma_f32_32x32x16_bf16(ah1, bh[s], C1, 0, 0, 0);
                C0 = __builtin_amdgcn_mfma_f32_32x32x16_bf16(ah0, blv,   C0, 0, 0, 0);
                C1 = __builtin_amdgcn_mfma_f32_32x32x16_bf16(ah1, blv,   C1, 0, 0, 0);
                C0 = __builtin_amdgcn_mfma_f32_32x32x16_bf16(al0, bh[s], C0, 0, 0, 0);
                C1 = __builtin_amdgcn_mfma_f32_32x32x16_bf16(al1, bh[s], C1, 0, 0, 0);
            }
            float colsum = 0.0f;
            #pragma unroll
            for (int r = 0; r < 16; ++r)
                colsum += fmaxf(C0[r] + b2v, 0.0f) + fmaxf(C1[r] + b2v, 0.0f);
            colsum += __shfl_xor(colsum, 32);
            if (lane < 32 && col < ED) sm.nin[g - 1][3 + col] = colsum;
        }
        __syncthreads();
    }

    // ---- zero hA/hB k-pads (aliased region is free now) ----
    for (int i = t; i < GN * 16; i += 512) {
        sm.u.tl.hA[i >> 4][100 + (i & 15)] = 0.0f;
        sm.u.tl.hB[i >> 4][100 + (i & 15)] = 0.0f;
    }
    __syncthreads();

    // ======== tail: batched node-MLP for all 32 nodes (split-bf16 MFMA) ========
    tail_layer<10, NIN, NSTR, ASTR>(&sm.nin[0][0],    &sm.u.tl.hA[0][0], nW1, nb1, wave, lane);
    __syncthreads();
    tail_layer<7, ND, ASTR, ASTR>(&sm.u.tl.hA[0][0], &sm.u.tl.hB[0][0], nW2, nb2, wave, lane);
    __syncthreads();
    tail_layer<7, ND, ASTR, CSTR>(&sm.u.tl.hB[0][0], &sm.u.tl.hC[0][0], nW3, nb3, wave, lane);
    __syncthreads();

    // ---- head: 32 nodes x 4 outputs on threads 0..127 ----
    if (t < GN * 4) {
        const int node = t >> 2, o = t & 3;
        float a = lb[o];
        #pragma unroll 10
        for (int k = 0; k < ND; ++k) a += sm.u.tl.hC[node][k] * lW[k * 4 + o];
        const int bn = b * N_ + n0 + node;
        float nv = V[bn * F_ + 1 + o] + a;
        if (o < 2) {
            nv = (nv >=  HALF) ? nv - BOXF : nv;
            nv = (nv <  -HALF) ? nv + BOXF : nv;
        }
        out[bn * 4 + o] = nv;
    }
}

extern "C" void kernel_launch(void* const* d_in, const int* in_sizes, int n_in,
                              void* d_out, int out_size, void* d_ws, size_t ws_size,
                              hipStream_t stream) {
    (void)in_sizes; (void)n_in; (void)d_ws; (void)ws_size; (void)out_size;
    const float* V   = (const float*)d_in[0];
    const float* dt  = (const float*)d_in[1];
    const float* eW1 = (const float*)d_in[2];
    const float* eb1 = (const float*)d_in[3];
    const float* eW2 = (const float*)d_in[4];
    const float* eb2 = (const float*)d_in[5];
    const float* nW1 = (const float*)d_in[6];
    const float* nb1 = (const float*)d_in[7];
    const float* nW2 = (const float*)d_in[8];
    const float* nb2 = (const float*)d_in[9];
    const float* nW3 = (const float*)d_in[10];
    const float* nb3 = (const float*)d_in[11];
    const float* lW  = (const float*)d_in[12];
    const float* lb  = (const float*)d_in[13];
    const int* Rs = (const int*)d_in[14];
    const int* Rr = (const int*)d_in[15];
    float* out = (float*)d_out;

    deltagn_v8<<<dim3(256), dim3(512), 0, stream>>>(
        V, dt, eW1, eb1, eW2, eb2, nW1, nb1, nW2, nb2, nW3, nb3, lW, lb, Rs, Rr, out);
}

// Round 9
// 484.886 us; speedup vs baseline: 3.5607x; 3.4177x over previous
//
#include <hip/hip_runtime.h>

#define B_    2
#define N_    4096
#define E_    262144
#define F_    5
#define ED    150
#define ND    100
#define NIN   154
#define EIN   9
#define GN    32      // nodes per block; grid = 2*4096/32 = 256 = 1 block/CU
#define WSTR  168     // w stride (336B = 21 16B-units, odd -> conflict-free b128 col reads)
#define HHSTR 168     // h_hi stride
#define HLSTR 160     // h_lo stride (320B; 4-way on reads - accepted to fit LDS)
#define NSTR  160     // f32 stride for nin (reads reach idx 159)
#define ASTR  112     // f32 stride for hA/hB (reads reach idx 111)
#define CSTR  104

typedef __attribute__((ext_vector_type(8)))  short bf16x8;
typedef __attribute__((ext_vector_type(16))) float f32x16;
typedef __attribute__((ext_vector_type(4)))  float f4;

static __device__ __forceinline__ unsigned short f2bf(float x) {
    unsigned int u = __float_as_uint(x);
    return (unsigned short)((u + 0x7fffu + ((u >> 16) & 1u)) >> 16);
}
static __device__ __forceinline__ float bf2f(unsigned short s) {
    return __uint_as_float(((unsigned int)s) << 16);
}
// swap bits 2<->3 of k so a lane's 8 frag elems are contiguous (one b128)
static __device__ __forceinline__ int kperm(int k) {
    return (k & ~12) | ((k & 4) << 1) | ((k & 8) >> 1);
}

struct __align__(16) SMem {
    union {
        struct {
            unsigned short h_hi[64][HHSTR];   // 21504 B
            unsigned short h_lo[64][HLSTR];   // 20480 B
        } lp;                                  // 41984 B (main loop)
        struct {
            float hA[GN][ASTR];               // 14336 B
            float hB[GN][ASTR];               // 14336 B
            float hC[GN][CSTR];               // 13312 B
        } tl;                                  // 41984 B (tail aliases loop region)
    } u;
    unsigned short w_hi[ED][WSTR];            // 50400 B  W2^T split-hi [col][kperm]
    unsigned short w_lo[ED][WSTR];            // 50400 B  W2^T split-lo
    float nin[GN][NSTR];                      // 20480 B  persists loop -> tail
};                                             // 163264 B <= 163840

// one tail MLP layer for 32 nodes: Y = relu(X @ Wg + bias), via 32x32x16 split-bf16 MFMA
template<int KS, int KR, int XS, int YS>
static __device__ __forceinline__ void tail_layer(const float* __restrict__ X,
                                                  float* __restrict__ Y,
                                                  const float* __restrict__ Wg,
                                                  const float* __restrict__ bias,
                                                  int wave, int lane)
{
    if (wave >= 4) return;
    const int jc  = wave * 32 + (lane & 31);
    const int hi  = lane >> 5;
    const int row = lane & 31;
    f32x16 C;
    #pragma unroll
    for (int r = 0; r < 16; ++r) C[r] = 0.0f;
    #pragma unroll
    for (int s = 0; s < KS; ++s) {
        bf16x8 ah, al, bhv, blv;
        f4 xa = *(const f4*)&X[row * XS + s * 16 + 4 * hi];
        f4 xb = *(const f4*)&X[row * XS + s * 16 + 8 + 4 * hi];
        #pragma unroll
        for (int e = 0; e < 8; ++e) {
            float x = (e < 4) ? xa[e] : xb[e - 4];
            unsigned short h = f2bf(x);
            ah[e] = (short)h;  al[e] = (short)f2bf(x - bf2f(h));
            int k = s * 16 + (e & 3) + 8 * (e >> 2) + 4 * hi;
            float w = (k < KR && jc < ND) ? Wg[k * ND + jc] : 0.0f;
            unsigned short wh = f2bf(w);
            bhv[e] = (short)wh;  blv[e] = (short)f2bf(w - bf2f(wh));
        }
        C = __builtin_amdgcn_mfma_f32_32x32x16_bf16(ah, bhv, C, 0, 0, 0);
        C = __builtin_amdgcn_mfma_f32_32x32x16_bf16(ah, blv, C, 0, 0, 0);
        C = __builtin_amdgcn_mfma_f32_32x32x16_bf16(al, bhv, C, 0, 0, 0);
    }
    if (jc < ND) {
        float bv = bias[jc];
        #pragma unroll
        for (int r = 0; r < 16; ++r) {
            int node = (r & 3) + 8 * (r >> 2) + 4 * hi;
            Y[node * YS + jc] = fmaxf(C[r] + bv, 0.0f);
        }
    }
}

__global__ __launch_bounds__(512, 1)
void deltagn_v9(const float* __restrict__ V,  const float* __restrict__ dt,
                const float* __restrict__ eW1, const float* __restrict__ eb1,
                const float* __restrict__ eW2, const float* __restrict__ eb2,
                const float* __restrict__ nW1, const float* __restrict__ nb1,
                const float* __restrict__ nW2, const float* __restrict__ nb2,
                const float* __restrict__ nW3, const float* __restrict__ nb3,
                const float* __restrict__ lW,  const float* __restrict__ lb,
                const int* __restrict__ Rs,   const int* __restrict__ Rr,
                float* __restrict__ out)
{
    __shared__ SMem sm;
    const int t    = threadIdx.x;
    const int wave = t >> 6;
    const int lane = t & 63;
    const int blk  = blockIdx.x;
    const int b    = blk >> 7;            // 128 blocks per batch
    const int n0   = (blk & 127) * GN;
    const float HALF = 3.0f, BOXF = 6.0f;
    const float dtv = dt[b];

    // int64-vs-int32 index detection (values < 4096 => odd int32 words all zero iff int64)
    const bool i64S = (__ballot(Rs[2 * lane + 1] == 0) == ~0ull);
    const bool i64R = (__ballot(Rr[2 * lane + 1] == 0) == ~0ull);

    // ---- zero nin and both w arrays (pads must be finite) ----
    {
        float* nf = &sm.nin[0][0];
        for (int i = t; i < GN * NSTR; i += 512) nf[i] = 0.0f;
        int4 z = {0, 0, 0, 0};
        int4* pz = (int4*)&sm.w_hi[0][0];          // w_hi + w_lo contiguous
        for (int i = t; i < (2 * ED * WSTR * 2) / 16; i += 512) pz[i] = z;
    }
    __syncthreads();

    // ---- stage W2 split hi/lo -> LDS, kperm'd [col][k'] ----
    for (int i = t; i < ED * ED; i += 512) {
        int k = i / ED, n = i - k * ED;            // eW2 is [k][n]
        float w = eW2[i];
        unsigned short hi = f2bf(w);
        int kp = kperm(k);
        sm.w_hi[n][kp] = hi;
        sm.w_lo[n][kp] = f2bf(w - bf2f(hi));
    }
    float b2v = 0.0f;
    if (wave < 5) {
        const int col = wave * 32 + (lane & 31);
        b2v = (col < ED) ? eb2[col] : 0.0f;
    }
    __syncthreads();

    // phase-B: one 16-col kstep of h = relu(Ein @ eW1 + eb1), split+pack to LDS
    auto phaseB = [&](const float (&ein)[EIN], int ks) {
        const int sb = ks * 16;
        float hv[16];
        #pragma unroll
        for (int r = 0; r < 16; ++r) {
            const int c  = sb + r;
            const int cs = (c < ED) ? c : 0;
            float a = eb1[cs];
            #pragma unroll
            for (int q = 0; q < EIN; ++q) a += ein[q] * eW1[q * ED + cs];
            hv[r] = (c < ED) ? fmaxf(a, 0.0f) : 0.0f;
        }
        constexpr int rm0[8] = {0,1,2,3,8,9,10,11};
        constexpr int rm1[8] = {4,5,6,7,12,13,14,15};
        bf16x8 h0, h1, l0, l1;
        #pragma unroll
        for (int e = 0; e < 8; ++e) {
            float x0 = hv[rm0[e]], x1 = hv[rm1[e]];
            unsigned short a0 = f2bf(x0), a1 = f2bf(x1);
            h0[e] = (short)a0;  l0[e] = (short)f2bf(x0 - bf2f(a0));
            h1[e] = (short)a1;  l1[e] = (short)f2bf(x1 - bf2f(a1));
        }
        *(bf16x8*)&sm.u.lp.h_hi[lane][sb + 0] = h0;
        *(bf16x8*)&sm.u.lp.h_hi[lane][sb + 8] = h1;
        *(bf16x8*)&sm.u.lp.h_lo[lane][sb + 0] = l0;
        *(bf16x8*)&sm.u.lp.h_lo[lane][sb + 8] = l1;
    };

    // ======== main loop: P = all waves produce h(g); C = waves 0-4 MFMA ========
    for (int g = 0; g < GN; ++g) {
        { // ---- phase P ----
            float ein[EIN];
            const int eb = b * E_ + (n0 + g) * 64 + lane;
            const int si = i64S ? Rs[2 * eb] : Rs[eb];
            const int ri = i64R ? Rr[2 * eb] : Rr[eb];
            const float* vs = V + (b * N_ + si) * F_;
            const float* vr = V + (b * N_ + ri) * F_;
            float d0 = vs[1] - vr[1], d1 = vs[2] - vr[2];
            d0 = (d0 >  HALF) ? d0 - BOXF : d0;
            d0 = (d0 <= -HALF) ? d0 + BOXF : d0;
            d1 = (d1 >  HALF) ? d1 - BOXF : d1;
            d1 = (d1 <= -HALF) ? d1 + BOXF : d1;
            ein[0] = vs[0]; ein[1] = vs[3]; ein[2] = vs[4];
            ein[3] = vr[0]; ein[4] = vr[3]; ein[5] = vr[4];
            ein[6] = d0;    ein[7] = d1;    ein[8] = dtv;

            if (wave < 5) {
                phaseB(ein, wave + 5);                 // ksteps 5..9
            } else if (wave == 5) {
                phaseB(ein, 0); phaseB(ein, 3);
            } else if (wave == 6) {
                phaseB(ein, 1); phaseB(ein, 4);
            } else {
                phaseB(ein, 2);
                if (lane < 4) {                        // nin extras for node g
                    const int bn5 = (b * N_ + n0 + g) * F_;
                    if (lane == 0) sm.nin[g][0]       = V[bn5 + 0];
                    if (lane == 1) sm.nin[g][1]       = V[bn5 + 3];
                    if (lane == 2) sm.nin[g][2]       = V[bn5 + 4];
                    if (lane == 3) sm.nin[g][NIN - 1] = dtv;
                }
            }
        }
        __syncthreads();

        if (wave < 5) { // ---- phase C: edge GEMM for node g, all operands streamed from LDS ----
            const int row  = lane & 31;
            const int col  = wave * 32 + (lane & 31);
            const int wrow = (col < ED) ? col : 0;     // clamp pad cols (results discarded)
            const int eoff = (lane >> 5) * 8;
            f32x16 C0, C1;
            #pragma unroll
            for (int r = 0; r < 16; ++r) { C0[r] = 0.0f; C1[r] = 0.0f; }
            #pragma unroll
            for (int s = 0; s < 10; ++s) {
                const int cb = s * 16 + eoff;
                bf16x8 bhv = *(const bf16x8*)&sm.w_hi[wrow][cb];
                bf16x8 blv = *(const bf16x8*)&sm.w_lo[wrow][cb];
                bf16x8 ah0 = *(const bf16x8*)&sm.u.lp.h_hi[row     ][cb];
                bf16x8 al0 = *(const bf16x8*)&sm.u.lp.h_lo[row     ][cb];
                bf16x8 ah1 = *(const bf16x8*)&sm.u.lp.h_hi[row + 32][cb];
                bf16x8 al1 = *(const bf16x8*)&sm.u.lp.h_lo[row + 32][cb];
                C0 = __builtin_amdgcn_mfma_f32_32x32x16_bf16(ah0, bhv, C0, 0, 0, 0);
                C1 = __builtin_amdgcn_mfma_f32_32x32x16_bf16(ah1, bhv, C1, 0, 0, 0);
                C0 = __builtin_amdgcn_mfma_f32_32x32x16_bf16(ah0, blv, C0, 0, 0, 0);
                C1 = __builtin_amdgcn_mfma_f32_32x32x16_bf16(ah1, blv, C1, 0, 0, 0);
                C0 = __builtin_amdgcn_mfma_f32_32x32x16_bf16(al0, bhv, C0, 0, 0, 0);
                C1 = __builtin_amdgcn_mfma_f32_32x32x16_bf16(al1, bhv, C1, 0, 0, 0);
            }
            float colsum = 0.0f;
            #pragma unroll
            for (int r = 0; r < 16; ++r)
                colsum += fmaxf(C0[r] + b2v, 0.0f) + fmaxf(C1[r] + b2v, 0.0f);
            colsum += __shfl_xor(colsum, 32);
            if (lane < 32 && col < ED) sm.nin[g][3 + col] = colsum;
        }
        __syncthreads();
    }

    // ---- zero hA/hB k-pads (aliased region now free; concurrent w/ L1, disjoint cols) ----
    for (int i = t; i < GN * 12; i += 512) {
        sm.u.tl.hA[i / 12][100 + (i % 12)] = 0.0f;
        sm.u.tl.hB[i / 12][100 + (i % 12)] = 0.0f;
    }

    // ======== tail: batched node-MLP for all 32 nodes (split-bf16 MFMA) ========
    tail_layer<10, NIN, NSTR, ASTR>(&sm.nin[0][0],    &sm.u.tl.hA[0][0], nW1, nb1, wave, lane);
    __syncthreads();
    tail_layer<7, ND, ASTR, ASTR>(&sm.u.tl.hA[0][0], &sm.u.tl.hB[0][0], nW2, nb2, wave, lane);
    __syncthreads();
    tail_layer<7, ND, ASTR, CSTR>(&sm.u.tl.hB[0][0], &sm.u.tl.hC[0][0], nW3, nb3, wave, lane);
    __syncthreads();

    // ---- head: 32 nodes x 4 outputs on threads 0..127 ----
    if (t < GN * 4) {
        const int node = t >> 2, o = t & 3;
        float a = lb[o];
        #pragma unroll 10
        for (int k = 0; k < ND; ++k) a += sm.u.tl.hC[node][k] * lW[k * 4 + o];
        const int bn = b * N_ + n0 + node;
        float nv = V[bn * F_ + 1 + o] + a;
        if (o < 2) {
            nv = (nv >=  HALF) ? nv - BOXF : nv;
            nv = (nv <  -HALF) ? nv + BOXF : nv;
        }
        out[bn * 4 + o] = nv;
    }
}

extern "C" void kernel_launch(void* const* d_in, const int* in_sizes, int n_in,
                              void* d_out, int out_size, void* d_ws, size_t ws_size,
                              hipStream_t stream) {
    (void)in_sizes; (void)n_in; (void)d_ws; (void)ws_size; (void)out_size;
    const float* V   = (const float*)d_in[0];
    const float* dt  = (const float*)d_in[1];
    const float* eW1 = (const float*)d_in[2];
    const float* eb1 = (const float*)d_in[3];
    const float* eW2 = (const float*)d_in[4];
    const float* eb2 = (const float*)d_in[5];
    const float* nW1 = (const float*)d_in[6];
    const float* nb1 = (const float*)d_in[7];
    const float* nW2 = (const float*)d_in[8];
    const float* nb2 = (const float*)d_in[9];
    const float* nW3 = (const float*)d_in[10];
    const float* nb3 = (const float*)d_in[11];
    const float* lW  = (const float*)d_in[12];
    const float* lb  = (const float*)d_in[13];
    const int* Rs = (const int*)d_in[14];
    const int* Rr = (const int*)d_in[15];
    float* out = (float*)d_out;

    deltagn_v9<<<dim3(256), dim3(512), 0, stream>>>(
        V, dt, eW1, eb1, eW2, eb2, nW1, nb1, nW2, nb2, nW3, nb3, lW, lb, Rs, Rr, out);
}